// Round 15
// baseline (1406.596 us; speedup 1.0000x reference)
//
#include <hip/hip_runtime.h>
#include <hip/hip_bf16.h>
#include <cstdint>
#include <cstddef>

typedef float  f32x4 __attribute__((ext_vector_type(4)));
typedef short  s16x8 __attribute__((ext_vector_type(8)));

#define NTOK   49
#define CDIM   192
#define HEADS  6
#define SCALE  0.17677669529663689f   // 1/sqrt(32)
#define LOG2E  1.4426950408889634f
#define SCL2   (0.17677669529663689f * 1.4426950408889634f)  // SCALE*LOG2E
#define PPB    4                       // window-pairs per block (persistent)

// d_ws layout: [biasT: 6*4096 f32 = 98304 B][wq_s: 576*192 u16 = 221184 B][wp_s: 192*192 u16 = 73728 B]
#define WS_BIAS_BYTES  98304
#define WS_WQ_BYTES    221184
#define WS_TOTAL_BYTES (WS_BIAS_BYTES + WS_WQ_BYTES + 73728)

static __device__ __forceinline__ ushort f2bf(float f) {
  __hip_bfloat16 h = __float2bfloat16(f);   // RNE, HW cvt
  union { __hip_bfloat16 h; ushort u; } c; c.h = h;
  return c.u;
}

static __device__ __forceinline__ ushort4 cvt4(float4 f) {
  union { ushort4 u; __hip_bfloat162 h[2]; } cc;
  cc.h[0] = __float22bfloat162_rn(make_float2(f.x, f.y));
  cc.h[1] = __float22bfloat162_rn(make_float2(f.z, f.w));
  return cc.u;
}

static __device__ __forceinline__ s16x8 pack8(f32x4 a, f32x4 b) {
  union { s16x8 v; __hip_bfloat162 h[4]; } u;
  u.h[0] = __float22bfloat162_rn(make_float2(a[0], a[1]));
  u.h[1] = __float22bfloat162_rn(make_float2(a[2], a[3]));
  u.h[2] = __float22bfloat162_rn(make_float2(b[0], b[1]));
  u.h[3] = __float22bfloat162_rn(make_float2(b[2], b[3]));
  return u.v;
}

static __device__ __forceinline__ f32x4 mfma_bf16(s16x8 a, s16x8 b, f32x4 c) {
  return __builtin_amdgcn_mfma_f32_16x16x32_bf16(a, b, c, 0, 0, 0);
}

// weights: fragment-major swizzle (n,k) -> ((n>>4)*6+(k>>5))*512 + ((k>>3)&3)*128 + (n&15)*8 + (k&7)
// biasT: fragment-major [h][qt][kt][lane][4], PREMULTIPLIED by LOG2E, key-mask baked in
__global__ void wconv_kernel(const float* __restrict__ qkv_w,
                             const float* __restrict__ proj_w,
                             const float* __restrict__ bias_table,
                             ushort* __restrict__ wqs, ushort* __restrict__ wps,
                             float* __restrict__ biasT) {
  int i = blockIdx.x * 256 + threadIdx.x;
  if (i < 576 * 192) {
    int n = i / 192, k = i % 192;
    int dst = ((n >> 4) * 6 + (k >> 5)) * 512 + ((k >> 3) & 3) * 128 + (n & 15) * 8 + (k & 7);
    wqs[dst] = f2bf(qkv_w[i]);
  }
  if (i < 192 * 192) {
    int n = i / 192, k = i % 192;
    int dst = ((n >> 4) * 6 + (k >> 5)) * 512 + ((k >> 3) & 3) * 128 + (n & 15) * 8 + (k & 7);
    wps[dst] = f2bf(proj_w[i]);
  }
  if (i < HEADS * 4096) {
    int h = i >> 12, r = i & 4095;
    int lane = (r >> 2) & 63, e = r & 3;
    int qt = r >> 10, kt = (r >> 8) & 3;
    int q   = qt * 16 + (lane & 15);
    int key = kt * 16 + (lane >> 4) * 4 + e;
    float v;
    if (key >= NTOK)      v = -1e30f;            // mask baked in
    else if (q >= NTOK)   v = 0.f;               // row unused; keep finite
    else {
      int qd = q / 7, qm = q % 7, kd = key / 7, km = key % 7;
      int ri = (qd - kd + 6) * 13 + (qm - km + 6);
      v = bias_table[ri * 6 + h] * LOG2E;        // log2-domain
    }
    biasT[i] = v;
  }
}

template <bool WB>
__global__ __launch_bounds__(768, 3)
void wattn_kernel(const float* __restrict__ x,
                  const float* __restrict__ qkv_w, const float* __restrict__ qkv_b,
                  const float* __restrict__ proj_w, const float* __restrict__ proj_b,
                  const float* __restrict__ bias_table,
                  const ushort* __restrict__ wqs, const ushort* __restrict__ wps,
                  const float* __restrict__ biasT,
                  float* __restrict__ out, int nwin) {
  // Persistent: PPB pairs/block, double-buffered x slots (parity).
  // 12 waves -> (3,3,3,3) SIMD packing. LDS: 2*2*25600 (+16) = 102,416 B (1 block/CU).
  __shared__ __align__(16) ushort XB[2][2][64 * 200]; // [parity][winl]: x; reused as attn_out
  __shared__ __align__(16) float  BL[WB ? 4 : 1024];  // bias_table (fallback path only)

  const int tid  = threadIdx.x;
  const int lane = tid & 63;
  const int wv   = tid >> 6;       // wave 0..11
  const int winl = wv / 6;         // window slot 0/1
  const int w    = wv - winl * 6;  // head id 0..5
  const int l16  = lane & 15;
  const int lk   = lane >> 4;      // 0..3
  const int h    = w;
  const int pair0 = blockIdx.x * PPB;

  // ---------------- initial stage: pair0 -> parity 0 ----------------------------
#pragma unroll
  for (int it = 0; it < 8; ++it) {
    int v = tid + it * 768;               // [0, 6144) covers 2x 64x192 in float4 units
    int wl2 = v / 3072, r = v - wl2 * 3072;
    int row = r / 48, c4 = r - row * 48;
    int wgl = pair0 * 2 + wl2;
    float4 f = {0.f, 0.f, 0.f, 0.f};
    if (row < NTOK && wgl < nwin)
      f = *(const float4*)(x + (size_t)wgl * (NTOK * CDIM) + row * CDIM + c4 * 4);
    *(ushort4*)&XB[0][wl2][row * 200 + c4 * 4] = cvt4(f);
  }
  if constexpr (!WB) {
    for (int v = tid; v < 169 * 6; v += 768) BL[v] = bias_table[v];
  }
  __syncthreads();

  for (int p = 0; p < PPB; ++p) {
    const int par = p & 1;
    const int win = (pair0 + p) * 2 + winl;
    const ushort* xb = XB[par][winl];

    // ---------------- phase 1: QKV GEMM in 2 passes ------------------------------
    s16x8 bq[4], ak[4], bv[2][2];

    // ---- Pass A: Q and K ----
    {
      f32x4 qacc[2][4] = {};
      f32x4 kacc[2][4] = {};
#pragma unroll
      for (int ks = 0; ks < 6; ++ks) {
        const int k0 = ks * 32 + lk * 8;
        s16x8 xa[4];
#pragma unroll
        for (int mt = 0; mt < 4; ++mt)
          xa[mt] = *(const s16x8*)&xb[(mt * 16 + l16) * 200 + k0];
#pragma unroll
        for (int nt2 = 0; nt2 < 2; ++nt2) {
          s16x8 wqf, wkf;
          if constexpr (WB) {
            const int lo = lk * 128 + l16 * 8;
            wqf = *(const s16x8*)&wqs[(((0 * 12 + w * 2 + nt2) * 6 + ks) << 9) + lo];
            wkf = *(const s16x8*)&wqs[(((1 * 12 + w * 2 + nt2) * 6 + ks) << 9) + lo];
          } else {
            const int nq = w * 32 + nt2 * 16 + l16;
            const float* pp;
            pp = qkv_w + (0 * 192 + nq) * 192 + k0;
            { float4 f0 = *(const float4*)pp, f1 = *(const float4*)(pp + 4);
              f32x4 a = {f0.x,f0.y,f0.z,f0.w}, b = {f1.x,f1.y,f1.z,f1.w}; wqf = pack8(a, b); }
            pp = qkv_w + (1 * 192 + nq) * 192 + k0;
            { float4 f0 = *(const float4*)pp, f1 = *(const float4*)(pp + 4);
              f32x4 a = {f0.x,f0.y,f0.z,f0.w}, b = {f1.x,f1.y,f1.z,f1.w}; wkf = pack8(a, b); }
          }
#pragma unroll
          for (int mt = 0; mt < 4; ++mt) {
            qacc[nt2][mt] = mfma_bf16(wqf, xa[mt], qacc[nt2][mt]);
            kacc[nt2][mt] = mfma_bf16(wkf, xa[mt], kacc[nt2][mt]);
          }
        }
      }
      const float4 b0 = *(const float4*)&qkv_b[0 * 192 + w * 32 +  0 + lk * 4];
      const float4 b1 = *(const float4*)&qkv_b[0 * 192 + w * 32 + 16 + lk * 4];
#pragma unroll
      for (int t = 0; t < 4; ++t) {
        f32x4 a0 = qacc[0][t], a1 = qacc[1][t];
        a0[0]=(a0[0]+b0.x)*SCL2; a0[1]=(a0[1]+b0.y)*SCL2; a0[2]=(a0[2]+b0.z)*SCL2; a0[3]=(a0[3]+b0.w)*SCL2;
        a1[0]=(a1[0]+b1.x)*SCL2; a1[1]=(a1[1]+b1.y)*SCL2; a1[2]=(a1[2]+b1.z)*SCL2; a1[3]=(a1[3]+b1.w)*SCL2;
        bq[t] = pack8(a0, a1);
      }
#pragma unroll
      for (int t = 0; t < 4; ++t)
        ak[t] = pack8(kacc[0][t], kacc[1][t]);   // K-bias dropped: softmax-invariant
    }

    // ---- Pass B: V ----
    {
      f32x4 vacc[4][2] = {};
#pragma unroll
      for (int ks = 0; ks < 6; ++ks) {
        const int k0 = ks * 32 + lk * 8;
        s16x8 xa[4];
#pragma unroll
        for (int mt = 0; mt < 4; ++mt)
          xa[mt] = *(const s16x8*)&xb[(mt * 16 + l16) * 200 + k0];
#pragma unroll
        for (int nt2 = 0; nt2 < 2; ++nt2) {
          s16x8 wf;
          if constexpr (WB) {
            wf = *(const s16x8*)&wqs[(((2 * 12 + w * 2 + nt2) * 6 + ks) << 9) + lk * 128 + l16 * 8];
          } else {
            const float* pp = qkv_w + (2 * 192 + w * 32 + nt2 * 16 + l16) * 192 + k0;
            float4 f0 = *(const float4*)pp, f1 = *(const float4*)(pp + 4);
            f32x4 a = {f0.x,f0.y,f0.z,f0.w}, b = {f1.x,f1.y,f1.z,f1.w}; wf = pack8(a, b);
          }
#pragma unroll
          for (int mt = 0; mt < 4; ++mt)
            vacc[mt][nt2] = mfma_bf16(xa[mt], wf, vacc[mt][nt2]);
        }
      }
#pragma unroll
      for (int nd = 0; nd < 2; ++nd) {
        const float vb = qkv_b[2 * 192 + w * 32 + nd * 16 + l16];
        f32x4 v0 = vacc[0][nd], v1 = vacc[1][nd], v2 = vacc[2][nd], v3 = vacc[3][nd];
#pragma unroll
        for (int i = 0; i < 4; ++i) { v0[i]+=vb; v1[i]+=vb; v2[i]+=vb; v3[i]+=vb; }
        bv[nd][0] = pack8(v0, v1);
        bv[nd][1] = pack8(v2, v3);
      }
    }

    // ---- T14 async-stage: issue next pair's x loads NOW (accs are dead) ---------
    const bool do_stage = (p + 1 < PPB);
    float4 st0, st1, st2, st3, st4, st5, st6, st7;
    if (do_stage) {
      const int np = pair0 + p + 1;
#pragma unroll
      for (int it = 0; it < 8; ++it) {
        int v = tid + it * 768;
        int wl2 = v / 3072, r = v - wl2 * 3072;
        int row = r / 48, c4 = r - row * 48;
        int wgl = np * 2 + wl2;
        float4 f = {0.f, 0.f, 0.f, 0.f};
        if (row < NTOK && wgl < nwin)
          f = *(const float4*)(x + (size_t)wgl * (NTOK * CDIM) + row * CDIM + c4 * 4);
        if (it == 0) st0 = f; else if (it == 1) st1 = f; else if (it == 2) st2 = f;
        else if (it == 3) st3 = f; else if (it == 4) st4 = f; else if (it == 5) st5 = f;
        else if (it == 6) st6 = f; else st7 = f;
      }
    }
    __syncthreads();   // barrier1: all x reads of this pair done; attn_out writes may begin

    // ---------------- phase 2: attention, streamed per 16-query tile -------------
    ushort* xbw = XB[par][winl];
#pragma unroll
    for (int qt = 0; qt < 4; ++qt) {
      f32x4 s[4];
#pragma unroll
      for (int kt = 0; kt < 4; ++kt) {
        f32x4 z = {0.f, 0.f, 0.f, 0.f};
        s[kt] = mfma_bf16(ak[kt], bq[qt], z);
      }
      float mx = -1e30f;
      if constexpr (WB) {
#pragma unroll
        for (int kt = 0; kt < 4; ++kt) {
          f32x4 b4 = *(const f32x4*)&biasT[h * 4096 + qt * 1024 + kt * 256 + lane * 4];
#pragma unroll
          for (int i = 0; i < 4; ++i) {
            float sv = s[kt][i] + b4[i];
            s[kt][i] = sv;
            mx = fmaxf(mx, sv);
          }
        }
      } else {
        const int q  = qt * 16 + l16;
        const int qd = q / 7, qm = q % 7;
#pragma unroll
        for (int kt = 0; kt < 4; ++kt)
#pragma unroll
          for (int i = 0; i < 4; ++i) {
            const int key = kt * 16 + lk * 4 + i;
            float sv = s[kt][i];
            if (key < NTOK) {
              int kd = key / 7, km = key % 7;
              int ri = (qd - kd + 6) * 13 + (qm - km + 6);
              ri = ri < 0 ? 0 : (ri > 168 ? 168 : ri);
              sv += BL[ri * 6 + h] * LOG2E;
            } else sv = -1e30f;
            s[kt][i] = sv;
            mx = fmaxf(mx, sv);
          }
      }
      mx = fmaxf(mx, __shfl_xor(mx, 16));
      mx = fmaxf(mx, __shfl_xor(mx, 32));
      float sum = 0.f;
#pragma unroll
      for (int kt = 0; kt < 4; ++kt)
#pragma unroll
        for (int i = 0; i < 4; ++i) {
          float pv = exp2f(s[kt][i] - mx);   // log2-domain
          s[kt][i] = pv; sum += pv;
        }
      sum += __shfl_xor(sum, 16);
      sum += __shfl_xor(sum, 32);
      const float rinv = 1.f / sum;
#pragma unroll
      for (int kt = 0; kt < 4; ++kt)
#pragma unroll
        for (int i = 0; i < 4; ++i) s[kt][i] *= rinv;

      s16x8 pa0 = pack8(s[0], s[1]);
      s16x8 pa1 = pack8(s[2], s[3]);
#pragma unroll
      for (int nd = 0; nd < 2; ++nd) {
        f32x4 z = {0.f, 0.f, 0.f, 0.f};
        f32x4 o = mfma_bf16(pa0, bv[nd][0], z);
        o = mfma_bf16(pa1, bv[nd][1], o);
#pragma unroll
        for (int i = 0; i < 4; ++i)
          xbw[(qt * 16 + lk * 4 + i) * 200 + h * 32 + nd * 16 + l16] = f2bf(o[i]);
      }
    }

    // ---- stage writes: next pair's x into other parity (loads now complete) ----
    if (do_stage) {
#pragma unroll
      for (int it = 0; it < 8; ++it) {
        int v = tid + it * 768;
        int wl2 = v / 3072, r = v - wl2 * 3072;
        int row = r / 48, c4 = r - row * 48;
        float4 f = (it == 0) ? st0 : (it == 1) ? st1 : (it == 2) ? st2 : (it == 3) ? st3
                 : (it == 4) ? st4 : (it == 5) ? st5 : (it == 6) ? st6 : st7;
        *(ushort4*)&XB[par ^ 1][wl2][row * 200 + c4 * 4] = cvt4(f);
      }
    }
    __syncthreads();   // barrier2: attn_out ready; next-pair x ready

    // ---------------- phase 3: proj GEMM (wave w -> cols [w*32, w*32+32)) -------
    {
      f32x4 pc[4][2] = {};
#pragma unroll
      for (int ks = 0; ks < 6; ++ks) {
        const int k0 = ks * 32 + lk * 8;
        s16x8 a[4];
#pragma unroll
        for (int mt = 0; mt < 4; ++mt)
          a[mt] = *(const s16x8*)&xb[(mt * 16 + l16) * 200 + k0];
#pragma unroll
        for (int nt = 0; nt < 2; ++nt) {
          s16x8 b;
          if constexpr (WB) {
            b = *(const s16x8*)&wps[(((w * 2 + nt) * 6 + ks) << 9) + lk * 128 + l16 * 8];
          } else {
            const int n = w * 32 + nt * 16 + l16;
            const float* pp = proj_w + n * 192 + k0;
            float4 f0 = *(const float4*)pp, f1 = *(const float4*)(pp + 4);
            f32x4 fa = {f0.x,f0.y,f0.z,f0.w}, fb = {f1.x,f1.y,f1.z,f1.w};
            b = pack8(fa, fb);
          }
#pragma unroll
          for (int mt = 0; mt < 4; ++mt)
            pc[mt][nt] = mfma_bf16(a[mt], b, pc[mt][nt]);
        }
      }
      if (win < nwin) {
#pragma unroll
        for (int nt = 0; nt < 2; ++nt) {
          const int n = w * 32 + nt * 16 + l16;
          const float pbias = proj_b[n];
#pragma unroll
          for (int mt = 0; mt < 4; ++mt)
#pragma unroll
            for (int i = 0; i < 4; ++i) {
              const int row = mt * 16 + lk * 4 + i;
              if (row < NTOK)
                out[((size_t)win * NTOK + row) * CDIM + n] = pc[mt][nt][i] + pbias;
            }
        }
      }
    }
    // no barrier: next iter's phase1 reads XB[par^1] (written before barrier2);
    // stage(p+2) ds_writes happen only after next iter's barrier1.
  }
}

extern "C" void kernel_launch(void* const* d_in, const int* in_sizes, int n_in,
                              void* d_out, int out_size, void* d_ws, size_t ws_size,
                              hipStream_t stream) {
  const float* x          = (const float*)d_in[0];
  const float* qkv_w      = (const float*)d_in[1];
  const float* qkv_b      = (const float*)d_in[2];
  const float* proj_w     = (const float*)d_in[3];
  const float* proj_b     = (const float*)d_in[4];
  const float* bias_table = (const float*)d_in[5];
  float* out = (float*)d_out;

  const int nwin   = in_sizes[0] / (NTOK * CDIM);   // 8192
  const int npairs = (nwin + 1) / 2;
  const int nblk   = (npairs + PPB - 1) / PPB;

  if (ws_size >= WS_TOTAL_BYTES) {
    float*  biasT = (float*)d_ws;
    ushort* wqs   = (ushort*)((char*)d_ws + WS_BIAS_BYTES);
    ushort* wps   = (ushort*)((char*)d_ws + WS_BIAS_BYTES + WS_WQ_BYTES);
    wconv_kernel<<<dim3(432), dim3(256), 0, stream>>>(qkv_w, proj_w, bias_table, wqs, wps, biasT);
    wattn_kernel<true><<<dim3(nblk), dim3(768), 0, stream>>>(
        x, qkv_w, qkv_b, proj_w, proj_b, bias_table, wqs, wps, biasT, out, nwin);
  } else {
    wattn_kernel<false><<<dim3(nblk), dim3(768), 0, stream>>>(
        x, qkv_w, qkv_b, proj_w, proj_b, bias_table, nullptr, nullptr, nullptr, out, nwin);
  }
}

// Round 16
// 420.741 us; speedup vs baseline: 3.3431x; 3.3431x over previous
//
#include <hip/hip_runtime.h>
#include <hip/hip_bf16.h>
#include <cstdint>
#include <cstddef>

typedef float  f32x4 __attribute__((ext_vector_type(4)));
typedef short  s16x8 __attribute__((ext_vector_type(8)));

#define NTOK   49
#define CDIM   192
#define HEADS  6
#define SCALE  0.17677669529663689f   // 1/sqrt(32)
#define LOG2E  1.4426950408889634f
#define SCL2   (0.17677669529663689f * 1.4426950408889634f)  // SCALE*LOG2E

// d_ws layout: [biasT: 6*4096 f32 = 98304 B][wq_s: 576*192 u16 = 221184 B][wp_s: 192*192 u16 = 73728 B]
#define WS_BIAS_BYTES  98304
#define WS_WQ_BYTES    221184
#define WS_TOTAL_BYTES (WS_BIAS_BYTES + WS_WQ_BYTES + 73728)

static __device__ __forceinline__ ushort f2bf(float f) {
  __hip_bfloat16 h = __float2bfloat16(f);   // RNE, HW cvt
  union { __hip_bfloat16 h; ushort u; } c; c.h = h;
  return c.u;
}

static __device__ __forceinline__ ushort4 pack4(f32x4 a) {
  union { ushort4 u; __hip_bfloat162 h[2]; } c;
  c.h[0] = __float22bfloat162_rn(make_float2(a[0], a[1]));
  c.h[1] = __float22bfloat162_rn(make_float2(a[2], a[3]));
  return c.u;
}

static __device__ __forceinline__ s16x8 pack8(f32x4 a, f32x4 b) {
  union { s16x8 v; __hip_bfloat162 h[4]; } u;
  u.h[0] = __float22bfloat162_rn(make_float2(a[0], a[1]));
  u.h[1] = __float22bfloat162_rn(make_float2(a[2], a[3]));
  u.h[2] = __float22bfloat162_rn(make_float2(b[0], b[1]));
  u.h[3] = __float22bfloat162_rn(make_float2(b[2], b[3]));
  return u.v;
}

static __device__ __forceinline__ f32x4 mfma_bf16(s16x8 a, s16x8 b, f32x4 c) {
  return __builtin_amdgcn_mfma_f32_16x16x32_bf16(a, b, c, 0, 0, 0);
}

// weights: fragment-major swizzle (n,k) -> ((n>>4)*6+(k>>5))*512 + ((k>>3)&3)*128 + (n&15)*8 + (k&7)
// biasT: fragment-major [h][qt][kt][lane][4], PREMULTIPLIED by LOG2E, key-mask baked in
__global__ void wconv_kernel(const float* __restrict__ qkv_w,
                             const float* __restrict__ proj_w,
                             const float* __restrict__ bias_table,
                             ushort* __restrict__ wqs, ushort* __restrict__ wps,
                             float* __restrict__ biasT) {
  int i = blockIdx.x * 256 + threadIdx.x;
  if (i < 576 * 192) {
    int n = i / 192, k = i % 192;
    int dst = ((n >> 4) * 6 + (k >> 5)) * 512 + ((k >> 3) & 3) * 128 + (n & 15) * 8 + (k & 7);
    wqs[dst] = f2bf(qkv_w[i]);
  }
  if (i < 192 * 192) {
    int n = i / 192, k = i % 192;
    int dst = ((n >> 4) * 6 + (k >> 5)) * 512 + ((k >> 3) & 3) * 128 + (n & 15) * 8 + (k & 7);
    wps[dst] = f2bf(proj_w[i]);
  }
  if (i < HEADS * 4096) {
    int h = i >> 12, r = i & 4095;
    int lane = (r >> 2) & 63, e = r & 3;
    int qt = r >> 10, kt = (r >> 8) & 3;
    int q   = qt * 16 + (lane & 15);
    int key = kt * 16 + (lane >> 4) * 4 + e;
    float v;
    if (key >= NTOK)      v = -1e30f;            // mask baked in
    else if (q >= NTOK)   v = 0.f;               // row unused; keep finite
    else {
      int qd = q / 7, qm = q % 7, kd = key / 7, km = key % 7;
      int ri = (qd - kd + 6) * 13 + (qm - km + 6);
      v = bias_table[ri * 6 + h] * LOG2E;        // log2-domain
    }
    biasT[i] = v;
  }
}

template <bool WB>
__global__ __launch_bounds__(768, 3)
void wattn_kernel(const float* __restrict__ x,
                  const float* __restrict__ qkv_w, const float* __restrict__ qkv_b,
                  const float* __restrict__ proj_w, const float* __restrict__ proj_b,
                  const float* __restrict__ bias_table,
                  const ushort* __restrict__ wqs, const ushort* __restrict__ wps,
                  const float* __restrict__ biasT,
                  float* __restrict__ out, int nwin) {
  // 2 windows/block, 12 waves -> (3,3,3,3) SIMD packing, 12 waves/CU resident.
  // LDS: 2*25600 (+16) = 51,216 B
  __shared__ __align__(16) ushort XB[2][64 * 200];   // x (bf16); reused as attn_out
  __shared__ __align__(16) float  BL[WB ? 4 : 1024]; // bias_table (fallback path only)

  const int tid  = threadIdx.x;
  const int lane = tid & 63;
  const int wv   = tid >> 6;       // wave 0..11
  const int winl = wv / 6;         // window slot 0/1
  const int w    = wv - winl * 6;  // head id 0..5
  const int l16  = lane & 15;
  const int lk   = lane >> 4;      // 0..3
  const int win  = blockIdx.x * 2 + winl;
  const int h    = w;

  // ---------------- phase 0: stage 2 windows of x -> bf16 LDS (zero pad rows) ---
#pragma unroll
  for (int it = 0; it < 8; ++it) {
    int v = tid + it * 768;               // [0, 6144) covers 2x 64x192 in float4 units
    int wl2 = v / 3072, r = v - wl2 * 3072;
    int row = r / 48, c4 = r - row * 48;
    int wgl = blockIdx.x * 2 + wl2;
    float4 f = {0.f, 0.f, 0.f, 0.f};
    if (row < NTOK && wgl < nwin)
      f = *(const float4*)(x + (size_t)wgl * (NTOK * CDIM) + row * CDIM + c4 * 4);
    union { ushort4 u; __hip_bfloat162 h[2]; } cc;
    cc.h[0] = __float22bfloat162_rn(make_float2(f.x, f.y));
    cc.h[1] = __float22bfloat162_rn(make_float2(f.z, f.w));
    *(ushort4*)&XB[wl2][row * 200 + c4 * 4] = cc.u;
  }
  if constexpr (!WB) {
    for (int v = tid; v < 169 * 6; v += 768) BL[v] = bias_table[v];
  }
  __syncthreads();

  // ---------------- phase 1: QKV GEMM in 2 passes (fits 170-reg bucket) ---------
  // Pass A: Q^T + K^T (64 AGPR acc); Pass B: V (32 AGPR acc, carries bq+ak).
  s16x8 bq[4], ak[4], bv[2][2];

  // ---- Pass A: Q and K ----
  {
    f32x4 qacc[2][4] = {};   // [dim-tile][tok-tile]
    f32x4 kacc[2][4] = {};
#pragma unroll
    for (int ks = 0; ks < 6; ++ks) {
      const int k0 = ks * 32 + lk * 8;
      s16x8 xa[4];
#pragma unroll
      for (int mt = 0; mt < 4; ++mt)
        xa[mt] = *(const s16x8*)&XB[winl][(mt * 16 + l16) * 200 + k0];
#pragma unroll
      for (int nt2 = 0; nt2 < 2; ++nt2) {
        s16x8 wqf, wkf;
        if constexpr (WB) {
          const int lo = lk * 128 + l16 * 8;
          wqf = *(const s16x8*)&wqs[(((0 * 12 + w * 2 + nt2) * 6 + ks) << 9) + lo];
          wkf = *(const s16x8*)&wqs[(((1 * 12 + w * 2 + nt2) * 6 + ks) << 9) + lo];
        } else {
          const int nq = w * 32 + nt2 * 16 + l16;
          const float* pp;
          pp = qkv_w + (0 * 192 + nq) * 192 + k0;
          { float4 f0 = *(const float4*)pp, f1 = *(const float4*)(pp + 4);
            f32x4 a = {f0.x,f0.y,f0.z,f0.w}, b = {f1.x,f1.y,f1.z,f1.w}; wqf = pack8(a, b); }
          pp = qkv_w + (1 * 192 + nq) * 192 + k0;
          { float4 f0 = *(const float4*)pp, f1 = *(const float4*)(pp + 4);
            f32x4 a = {f0.x,f0.y,f0.z,f0.w}, b = {f1.x,f1.y,f1.z,f1.w}; wkf = pack8(a, b); }
        }
#pragma unroll
        for (int mt = 0; mt < 4; ++mt) {
          qacc[nt2][mt] = mfma_bf16(wqf, xa[mt], qacc[nt2][mt]);
          kacc[nt2][mt] = mfma_bf16(wkf, xa[mt], kacc[nt2][mt]);
        }
      }
    }
    // epilogue Q -> bq (fold SCALE*LOG2E; log2-domain softmax)
    {
      const float4 b0 = *(const float4*)&qkv_b[0 * 192 + w * 32 +  0 + lk * 4];
      const float4 b1 = *(const float4*)&qkv_b[0 * 192 + w * 32 + 16 + lk * 4];
#pragma unroll
      for (int t = 0; t < 4; ++t) {
        f32x4 a0 = qacc[0][t], a1 = qacc[1][t];
        a0[0]=(a0[0]+b0.x)*SCL2; a0[1]=(a0[1]+b0.y)*SCL2; a0[2]=(a0[2]+b0.z)*SCL2; a0[3]=(a0[3]+b0.w)*SCL2;
        a1[0]=(a1[0]+b1.x)*SCL2; a1[1]=(a1[1]+b1.y)*SCL2; a1[2]=(a1[2]+b1.z)*SCL2; a1[3]=(a1[3]+b1.w)*SCL2;
        bq[t] = pack8(a0, a1);
      }
    }
    // epilogue K -> ak (NO K-bias: q.kb is per-query constant -> softmax-invariant)
#pragma unroll
    for (int t = 0; t < 4; ++t)
      ak[t] = pack8(kacc[0][t], kacc[1][t]);
  }

  // ---- Pass B: V (carries bq + ak) ----
  {
    f32x4 vacc[4][2] = {};   // [tok-tile][dim-tile]
#pragma unroll
    for (int ks = 0; ks < 6; ++ks) {
      const int k0 = ks * 32 + lk * 8;
      s16x8 xa[4];
#pragma unroll
      for (int mt = 0; mt < 4; ++mt)
        xa[mt] = *(const s16x8*)&XB[winl][(mt * 16 + l16) * 200 + k0];
#pragma unroll
      for (int nt2 = 0; nt2 < 2; ++nt2) {
        s16x8 wf;
        if constexpr (WB) {
          wf = *(const s16x8*)&wqs[(((2 * 12 + w * 2 + nt2) * 6 + ks) << 9) + lk * 128 + l16 * 8];
        } else {
          const float* pp = qkv_w + (2 * 192 + w * 32 + nt2 * 16 + l16) * 192 + k0;
          float4 f0 = *(const float4*)pp, f1 = *(const float4*)(pp + 4);
          f32x4 a = {f0.x,f0.y,f0.z,f0.w}, b = {f1.x,f1.y,f1.z,f1.w}; wf = pack8(a, b);
        }
#pragma unroll
        for (int mt = 0; mt < 4; ++mt)
          vacc[mt][nt2] = mfma_bf16(xa[mt], wf, vacc[mt][nt2]);
      }
    }
#pragma unroll
    for (int nd = 0; nd < 2; ++nd) {
      const float vb = qkv_b[2 * 192 + w * 32 + nd * 16 + l16];
      f32x4 v0 = vacc[0][nd], v1 = vacc[1][nd], v2 = vacc[2][nd], v3 = vacc[3][nd];
#pragma unroll
      for (int i = 0; i < 4; ++i) { v0[i]+=vb; v1[i]+=vb; v2[i]+=vb; v3[i]+=vb; }
      bv[nd][0] = pack8(v0, v1);
      bv[nd][1] = pack8(v2, v3);
    }
  }
  __syncthreads();   // all XB (x) reads done; XB reusable for attn_out

  // ---------------- phase 2: attention, streamed per 16-query tile --------------
  // S^T = K . Q^T (log2 domain): s[kt] with col=l16=query, row=lk*4+i=key.
  // PV operand-swapped: O^T = mfma(bv, pa) -> col=l16=query, row=lk*4+i=dim;
  // rinv (per-query = per-lane) folds into O post-PV; XB write is one ushort4.
  ushort* xbw = XB[winl];
#pragma unroll
  for (int qt = 0; qt < 4; ++qt) {
    f32x4 s[4];
#pragma unroll
    for (int kt = 0; kt < 4; ++kt) {
      f32x4 z = {0.f, 0.f, 0.f, 0.f};
      s[kt] = mfma_bf16(ak[kt], bq[qt], z);
    }
    float mx = -1e30f;
    if constexpr (WB) {
#pragma unroll
      for (int kt = 0; kt < 4; ++kt) {
        f32x4 b4 = *(const f32x4*)&biasT[h * 4096 + qt * 1024 + kt * 256 + lane * 4];
#pragma unroll
        for (int i = 0; i < 4; ++i) {
          float sv = s[kt][i] + b4[i];
          s[kt][i] = sv;
          mx = fmaxf(mx, sv);
        }
      }
    } else {
      const int q  = qt * 16 + l16;
      const int qd = q / 7, qm = q % 7;
#pragma unroll
      for (int kt = 0; kt < 4; ++kt)
#pragma unroll
        for (int i = 0; i < 4; ++i) {
          const int key = kt * 16 + lk * 4 + i;
          float sv = s[kt][i];
          if (key < NTOK) {
            int kd = key / 7, km = key % 7;
            int ri = (qd - kd + 6) * 13 + (qm - km + 6);
            ri = ri < 0 ? 0 : (ri > 168 ? 168 : ri);
            sv += BL[ri * 6 + h] * LOG2E;
          } else sv = -1e30f;
          s[kt][i] = sv;
          mx = fmaxf(mx, sv);
        }
    }
    mx = fmaxf(mx, __shfl_xor(mx, 16));
    mx = fmaxf(mx, __shfl_xor(mx, 32));
    float sum = 0.f;
#pragma unroll
    for (int kt = 0; kt < 4; ++kt)
#pragma unroll
      for (int i = 0; i < 4; ++i) {
        float pv = exp2f(s[kt][i] - mx);   // log2-domain; unnormalized P in (0,1]
        s[kt][i] = pv; sum += pv;
      }
    sum += __shfl_xor(sum, 16);
    sum += __shfl_xor(sum, 32);
    const float rinv = 1.f / sum;          // per-lane: this lane's query = qt*16+l16

    s16x8 pa0 = pack8(s[0], s[1]);
    s16x8 pa1 = pack8(s[2], s[3]);
#pragma unroll
    for (int nd = 0; nd < 2; ++nd) {
      f32x4 z = {0.f, 0.f, 0.f, 0.f};
      f32x4 o = mfma_bf16(bv[nd][0], pa0, z);   // swapped: O^T[dim][query]
      o = mfma_bf16(bv[nd][1], pa1, o);
      o[0] *= rinv; o[1] *= rinv; o[2] *= rinv; o[3] *= rinv;
      *(ushort4*)&xbw[(qt * 16 + l16) * 200 + h * 32 + nd * 16 + lk * 4] = pack4(o);
    }
  }
  __syncthreads();   // attn_out fully written to XB

  // ---------------- phase 3: proj GEMM, operand-swapped (float4 stores) ---------
  {
    f32x4 pc[2][4] = {};   // [nt][mt]: col=l16=token, row=lk*4+i=channel
#pragma unroll
    for (int ks = 0; ks < 6; ++ks) {
      const int k0 = ks * 32 + lk * 8;
      s16x8 a[4];
#pragma unroll
      for (int mt = 0; mt < 4; ++mt)
        a[mt] = *(const s16x8*)&XB[winl][(mt * 16 + l16) * 200 + k0];
#pragma unroll
      for (int nt = 0; nt < 2; ++nt) {
        s16x8 b;
        if constexpr (WB) {
          b = *(const s16x8*)&wps[(((w * 2 + nt) * 6 + ks) << 9) + lk * 128 + l16 * 8];
        } else {
          const int n = w * 32 + nt * 16 + l16;
          const float* pp = proj_w + n * 192 + k0;
          float4 f0 = *(const float4*)pp, f1 = *(const float4*)(pp + 4);
          f32x4 fa = {f0.x,f0.y,f0.z,f0.w}, fb = {f1.x,f1.y,f1.z,f1.w};
          b = pack8(fa, fb);
        }
#pragma unroll
        for (int mt = 0; mt < 4; ++mt)
          pc[nt][mt] = mfma_bf16(b, a[mt], pc[nt][mt]);   // swapped
      }
    }
    if (win < nwin) {
#pragma unroll
      for (int nt = 0; nt < 2; ++nt) {
        const float4 pb4 = *(const float4*)&proj_b[w * 32 + nt * 16 + lk * 4];
#pragma unroll
        for (int mt = 0; mt < 4; ++mt) {
          const int row = mt * 16 + l16;
          if (row < NTOK) {
            f32x4 o = pc[nt][mt];
            o[0] += pb4.x; o[1] += pb4.y; o[2] += pb4.z; o[3] += pb4.w;
            *(float4*)&out[((size_t)win * NTOK + row) * CDIM + w * 32 + nt * 16 + lk * 4] =
                make_float4(o[0], o[1], o[2], o[3]);
          }
        }
      }
    }
  }
}

extern "C" void kernel_launch(void* const* d_in, const int* in_sizes, int n_in,
                              void* d_out, int out_size, void* d_ws, size_t ws_size,
                              hipStream_t stream) {
  const float* x          = (const float*)d_in[0];
  const float* qkv_w      = (const float*)d_in[1];
  const float* qkv_b      = (const float*)d_in[2];
  const float* proj_w     = (const float*)d_in[3];
  const float* proj_b     = (const float*)d_in[4];
  const float* bias_table = (const float*)d_in[5];
  float* out = (float*)d_out;

  const int nwin = in_sizes[0] / (NTOK * CDIM);   // 8192
  const int nblk = (nwin + 1) / 2;

  if (ws_size >= WS_TOTAL_BYTES) {
    float*  biasT = (float*)d_ws;
    ushort* wqs   = (ushort*)((char*)d_ws + WS_BIAS_BYTES);
    ushort* wps   = (ushort*)((char*)d_ws + WS_BIAS_BYTES + WS_WQ_BYTES);
    wconv_kernel<<<dim3(432), dim3(256), 0, stream>>>(qkv_w, proj_w, bias_table, wqs, wps, biasT);
    wattn_kernel<true><<<dim3(nblk), dim3(768), 0, stream>>>(
        x, qkv_w, qkv_b, proj_w, proj_b, bias_table, wqs, wps, biasT, out, nwin);
  } else {
    wattn_kernel<false><<<dim3(nblk), dim3(768), 0, stream>>>(
        x, qkv_w, qkv_b, proj_w, proj_b, bias_table, nullptr, nullptr, nullptr, out, nwin);
  }
}